// Round 8
// baseline (171.551 us; speedup 1.0000x reference)
//
#include <hip/hip_runtime.h>
#include <math.h>

// img (8, 3, 1024, 2048) fp32 -> same-shape fp32 output.
// Round-5 lockstep skeleton + 2-row pipeline bodies (ILP x2, half the barriers).
#define Wd 2048
#define Hd 1024
#define BC 24
#define CH 32          // output rows per block chunk (y0 % 8 == 0)
#define NT 512         // 8 waves; lane owns 4 consecutive cols
#define NW 8
#define SROW (Wd + 8)  // LDS img row: col c at index c+4 (zero halo +-4)

__device__ __forceinline__ float4 f4s(float v) { return make_float4(v, v, v, v); }

// Exact-equivalent rewrite of the reference masking (verified rounds 4-6, absmax 0).
__device__ __forceinline__ float masked_grad1(float g1, float g2, float g3) {
    const float HALF_T     = (float)(0.5 / 1023.0);
    const float GRD_BOTTOM = (float)(1.0 / 1023.0);
    const float GRD_UP     = (float)(4.0 / 1023.0);
    const float THIRD      = (float)(1.0 / 3.0);
    float m  = (g1 + g2 + g3) * THIRD;
    float lo = m - HALF_T;
    float hi = m + HALF_T;
    float a  = fabsf(g1);
    bool keep = (g1 >= lo) & (g1 <= hi) & (a >= GRD_BOTTOM) & (a <= GRD_UP);
    return keep ? g1 : 0.0f;
}

// One gradmap row: ce/lf/rt give the x-halo; (a_k, b_k) give y diffs a_k - b_k.
__device__ __forceinline__ float4 grad_row(float4 ce, float4 lf, float4 rt,
        float4 a1, float4 b1, float4 a2, float4 b2, float4 a3, float4 b3) {
    const float K = 255.75f;  // 1023/4 exact
    float gx0 = masked_grad1(ce.y - lf.w, ce.z - lf.z, ce.w - lf.y);
    float gx1 = masked_grad1(ce.z - ce.x, ce.w - lf.w, rt.x - lf.z);
    float gx2 = masked_grad1(ce.w - ce.y, rt.x - ce.x, rt.y - lf.w);
    float gx3 = masked_grad1(rt.x - ce.z, rt.y - ce.y, rt.z - ce.x);
    float gy0 = masked_grad1(a1.x - b1.x, a2.x - b2.x, a3.x - b3.x);
    float gy1 = masked_grad1(a1.y - b1.y, a2.y - b2.y, a3.y - b3.y);
    float gy2 = masked_grad1(a1.z - b1.z, a2.z - b2.z, a3.z - b3.z);
    float gy3 = masked_grad1(a1.w - b1.w, a2.w - b2.w, a3.w - b3.w);
    float4 g;
    g.x = fmaxf(fabsf(gx0), fabsf(gy0)) * K;
    g.y = fmaxf(fabsf(gx1), fabsf(gy1)) * K;
    g.z = fmaxf(fabsf(gx2), fabsf(gy2)) * K;
    g.w = fmaxf(fabsf(gx3), fabsf(gy3)) * K;
    return g;
}

__device__ __forceinline__ float4 hmax3(float4 g, float eL, float eR, int lane) {
    float gl = __shfl_up(g.w, 1, 64);   if (lane == 0)  gl = eL;
    float gr = __shfl_down(g.x, 1, 64); if (lane == 63) gr = eR;
    float4 h;
    h.x = fmaxf(fmaxf(gl,  g.x), g.y);
    h.y = fmaxf(fmaxf(g.x, g.y), g.z);
    h.z = fmaxf(fmaxf(g.y, g.z), g.w);
    h.w = fmaxf(fmaxf(g.z, g.w), gr);
    return h;
}
__device__ __forceinline__ float4 hmin3(float4 g, float eL, float eR, int lane) {
    float gl = __shfl_up(g.w, 1, 64);   if (lane == 0)  gl = eL;
    float gr = __shfl_down(g.x, 1, 64); if (lane == 63) gr = eR;
    float4 h;
    h.x = fminf(fminf(gl,  g.x), g.y);
    h.y = fminf(fminf(g.x, g.y), g.z);
    h.z = fminf(fminf(g.y, g.z), g.w);
    h.w = fminf(fminf(g.z, g.w), gr);
    return h;
}
__device__ __forceinline__ float4 max3v(float4 a, float4 b, float4 c) {
    float4 r;
    r.x = fmaxf(fmaxf(a.x, b.x), c.x); r.y = fmaxf(fmaxf(a.y, b.y), c.y);
    r.z = fmaxf(fmaxf(a.z, b.z), c.z); r.w = fmaxf(fmaxf(a.w, b.w), c.w);
    return r;
}
__device__ __forceinline__ float4 min3v(float4 a, float4 b, float4 c) {
    float4 r;
    r.x = fminf(fminf(a.x, b.x), c.x); r.y = fminf(fminf(a.y, b.y), c.y);
    r.z = fminf(fminf(a.z, b.z), c.z); r.w = fminf(fminf(a.w, b.w), c.w);
    return r;
}

struct State {
    float4 im[8];      // img rows T-6..T+1; row r in slot r&7 (compile-time)
    float4 vp[2][2];   // prefetch: slot (T/2)&1 holds rows {T, T+1}; 4 rows in flight
    float4 g[2][2];    // grad pairs by body parity
    float4 h[2][2];    // hmax pairs
    float4 v[2][2];    // vmax pairs
    float4 n[2][2];    // hmin pairs
};

// LDS-visibility barrier WITHOUT the vmcnt(0) drain __syncthreads would add:
// global prefetch loads stay in flight across bodies.
__device__ __forceinline__ void row_barrier() {
    asm volatile("s_waitcnt lgkmcnt(0)" ::: "memory");
    __builtin_amdgcn_s_barrier();
    asm volatile("" ::: "memory");
}

// One 2-row body; T even, PM4 == (T/2) & 3 (compile-time since y0 % 8 == 0).
// Stages: consume img rows T,T+1 / issue loads T+4,T+5 / grad T-3,T-2 /
// hmax T-5,T-4 / vmax T-6,T-5 / hmin T-8,T-7 / out T-9,T-8.
// SM: 0 = no store, 1 = store only row T-8, 2 = both, 3 = only row T-9 (last body).
template<int PM4, bool RE, int SM>
__device__ __forceinline__ void body(int T, State& S,
        const float* __restrict__ ip, float* __restrict__ op,
        int lane, int wv, int c0,
        float (*sE)[SROW], float (*sO)[SROW],
        float (*gLp)[2][NW], float (*gRp)[2][NW],
        float (*vLp)[2][NW], float (*vRp)[2][NW]) {
    constexpr int PW  = PM4 & 1;        // this body's parity
    constexpr int PR  = PW ^ 1;         // previous body's parity
    constexpr int EWs = PM4 & 1;        // even-img ring write slot (row T)
    constexpr int ERs = (PM4 + 1) & 1;  // even-img read slot (row T-2)
    constexpr int OWs = PM4 & 3;        // odd-img ring write slot (row T+1)
    constexpr int ORs = (PM4 + 2) & 3;  // odd-img read slot (row T-3)

    // cross-wave edge scalars published by the previous body (1 barrier old)
    float egl0 = (wv > 0)      ? gRp[PR][0][wv - 1] : -INFINITY;  // grad T-5
    float egr0 = (wv < NW - 1) ? gLp[PR][0][wv + 1] : -INFINITY;
    float egl1 = (wv > 0)      ? gRp[PR][1][wv - 1] : -INFINITY;  // grad T-4
    float egr1 = (wv < NW - 1) ? gLp[PR][1][wv + 1] : -INFINITY;
    float evl0 = (wv > 0)      ? vRp[PR][0][wv - 1] : INFINITY;   // vmax T-8
    float evr0 = (wv < NW - 1) ? vLp[PR][0][wv + 1] : INFINITY;
    float evl1 = (wv > 0)      ? vRp[PR][1][wv - 1] : INFINITY;   // vmax T-7
    float evr1 = (wv < NW - 1) ? vLp[PR][1][wv + 1] : INFINITY;

    // consume prefetched rows T, T+1; publish to LDS rings; issue rows T+4, T+5
    float4 v0 = S.vp[PW][0];
    float4 v1 = S.vp[PW][1];
    S.im[(2 * PM4 + 16) & 7] = v0;
    S.im[(2 * PM4 + 17) & 7] = v1;
    *(float4*)&sE[EWs][c0 + 4] = v0;
    *(float4*)&sO[OWs][c0 + 4] = v1;
    {
        float4 a = f4s(0.f), b = f4s(0.f);
        if (!RE || (unsigned)(T + 4) < (unsigned)Hd)
            a = *(const float4*)(ip + (size_t)(T + 4) * Wd);
        if (!RE || (unsigned)(T + 5) < (unsigned)Hd)
            b = *(const float4*)(ip + (size_t)(T + 5) * Wd);
        S.vp[PW][0] = a; S.vp[PW][1] = b;
    }

    // ---- grads: rows T-3 (odd ring, 2 barriers old) and T-2 (even ring, 1 old)
    float4 lf0 = *(const float4*)&sO[ORs][c0];
    float4 rt0 = *(const float4*)&sO[ORs][c0 + 8];
    float4 lf1 = *(const float4*)&sE[ERs][c0];
    float4 rt1 = *(const float4*)&sE[ERs][c0 + 8];
    float4 gv0 = grad_row(S.im[(2 * PM4 + 13) & 7], lf0, rt0,   // ce = row T-3
                          S.im[(2 * PM4 + 14) & 7], S.im[(2 * PM4 + 12) & 7],   // T-2 - T-4
                          S.im[(2 * PM4 + 15) & 7], S.im[(2 * PM4 + 11) & 7],   // T-1 - T-5
                          v0,                       S.im[(2 * PM4 + 10) & 7]);  // T   - T-6
    float4 gv1 = grad_row(S.im[(2 * PM4 + 14) & 7], lf1, rt1,   // ce = row T-2
                          S.im[(2 * PM4 + 15) & 7], S.im[(2 * PM4 + 13) & 7],   // T-1 - T-3
                          v0,                       S.im[(2 * PM4 + 12) & 7],   // T   - T-4
                          v1,                       S.im[(2 * PM4 + 11) & 7]);  // T+1 - T-5

    // ---- hmax rows T-5, T-4 (prev body's grads + 1-barrier-old edges)
    float4 hm0 = hmax3(S.g[PR][0], egl0, egr0, lane);
    float4 hm1 = hmax3(S.g[PR][1], egl1, egr1, lane);
    if (RE) {
        if ((unsigned)(T - 5) >= (unsigned)Hd) hm0 = f4s(-INFINITY);
        if ((unsigned)(T - 4) >= (unsigned)Hd) hm1 = f4s(-INFINITY);
    }

    // ---- vmax rows T-6, T-5
    float4 vm0 = max3v(S.h[PR][0], S.h[PR][1], hm0);
    float4 vm1 = max3v(S.h[PR][1], hm0, hm1);
    if (RE) {
        if ((unsigned)(T - 6) >= (unsigned)Hd) vm0 = f4s(INFINITY);
        if ((unsigned)(T - 5) >= (unsigned)Hd) vm1 = f4s(INFINITY);
    }

    // ---- hmin rows T-8, T-7 (prev body's vmax + edges)
    float4 hn0 = hmin3(S.v[PR][0], evl0, evr0, lane);
    float4 hn1 = hmin3(S.v[PR][1], evl1, evr1, lane);

    // ---- out rows T-9, T-8
    if (SM == 2 || SM == 3) {
        float4 o0 = min3v(S.n[PR][0], S.n[PR][1], hn0);
        *(float4*)(op + (size_t)(T - 9) * Wd) = o0;
    }
    if (SM == 1 || SM == 2) {
        float4 o1 = min3v(S.n[PR][1], hn0, hn1);
        *(float4*)(op + (size_t)(T - 8) * Wd) = o1;
    }

    // ---- ring updates
    S.g[PW][0] = gv0; S.g[PW][1] = gv1;
    S.h[PW][0] = hm0; S.h[PW][1] = hm1;
    S.v[PW][0] = vm0; S.v[PW][1] = vm1;
    S.n[PW][0] = hn0; S.n[PW][1] = hn1;

    if (SM != 3) {  // last body feeds nothing
        if (lane == 0)  { gLp[PW][0][wv] = gv0.x; gLp[PW][1][wv] = gv1.x;
                          vLp[PW][0][wv] = vm0.x; vLp[PW][1][wv] = vm1.x; }
        if (lane == 63) { gRp[PW][0][wv] = gv0.w; gRp[PW][1][wv] = gv1.w;
                          vRp[PW][0][wv] = vm0.w; vRp[PW][1][wv] = vm1.w; }
        row_barrier();
    }
}

template<bool RE>
__device__ __forceinline__ void sweep(
        const float* __restrict__ ip, float* __restrict__ op, int y0,
        int tid, int lane, int wv, int c0,
        float (*sE)[SROW], float (*sO)[SROW],
        float (*gLp)[2][NW], float (*gRp)[2][NW],
        float (*vLp)[2][NW], float (*vRp)[2][NW]) {
    // ---- constant zero halo columns for BOTH img rings (the round-7 bug:
    //      these were missing -> garbage entered _dshift's zero padding).
    //      In-loop writes cover only [4, Wd+3]; halos [0..3] and [Wd+4..Wd+7].
    if (tid < 48) {
        int r = tid >> 3, j = tid & 7;
        int col = (j < 4) ? j : (Wd + j);
        if (r < 2) sE[r][col] = 0.0f;
        else       sO[r - 2][col] = 0.0f;
    }

    State S;
    #pragma unroll
    for (int i = 0; i < 8; ++i) S.im[i] = f4s(0.f);
    S.g[0][0] = S.g[0][1] = S.g[1][0] = S.g[1][1] = f4s(0.f);
    S.h[0][0] = S.h[0][1] = S.h[1][0] = S.h[1][1] = f4s(-INFINITY);
    S.v[0][0] = S.v[0][1] = S.v[1][0] = S.v[1][1] = f4s(INFINITY);
    S.n[0][0] = S.n[0][1] = S.n[1][0] = S.n[1][1] = f4s(INFINITY);

    // ---- prime: img rows y0-6 .. y0-1 (registers) + LDS rows y0-3,y0-2,y0-1
    #pragma unroll
    for (int r = 0; r < 6; ++r) {
        int row = y0 - 6 + r;
        float4 v = f4s(0.f);
        if (!RE || row >= 0) v = *(const float4*)(ip + (size_t)row * Wd);
        S.im[(r + 2) & 7] = v;
        if (r == 3) *(float4*)&sO[2][c0 + 4] = v;  // row y0-3 (odd, slot ((y0-4)/2)&3 = 2)
        if (r == 4) *(float4*)&sE[1][c0 + 4] = v;  // row y0-2 (even, slot ((y0-2)/2)&1 = 1)
        if (r == 5) *(float4*)&sO[3][c0 + 4] = v;  // row y0-1 (odd, slot ((y0-2)/2)&3 = 3)
    }
    // prefetch rows y0..y0+3 (always valid image rows; y0 <= 992)
    S.vp[0][0] = *(const float4*)(ip + (size_t)(y0 + 0) * Wd);
    S.vp[0][1] = *(const float4*)(ip + (size_t)(y0 + 1) * Wd);
    S.vp[1][0] = *(const float4*)(ip + (size_t)(y0 + 2) * Wd);
    S.vp[1][1] = *(const float4*)(ip + (size_t)(y0 + 3) * Wd);
    __syncthreads();

    // ---- warm-up: 4 bodies, no store
    body<0, RE, 0>(y0 + 0, S, ip, op, lane, wv, c0, sE, sO, gLp, gRp, vLp, vRp);
    body<1, RE, 0>(y0 + 2, S, ip, op, lane, wv, c0, sE, sO, gLp, gRp, vLp, vRp);
    body<2, RE, 0>(y0 + 4, S, ip, op, lane, wv, c0, sE, sO, gLp, gRp, vLp, vRp);
    body<3, RE, 0>(y0 + 6, S, ip, op, lane, wv, c0, sE, sO, gLp, gRp, vLp, vRp);
    // first store body: stores only row y0 (row y0-1 is outside the chunk)
    body<0, RE, 1>(y0 + 8, S, ip, op, lane, wv, c0, sE, sO, gLp, gRp, vLp, vRp);

    // ---- steady: 15 full-store bodies
    #pragma unroll 1
    for (int j = 0; j < 3; ++j) {
        int T = y0 + 10 + j * 8;
        body<1, RE, 2>(T + 0, S, ip, op, lane, wv, c0, sE, sO, gLp, gRp, vLp, vRp);
        body<2, RE, 2>(T + 2, S, ip, op, lane, wv, c0, sE, sO, gLp, gRp, vLp, vRp);
        body<3, RE, 2>(T + 4, S, ip, op, lane, wv, c0, sE, sO, gLp, gRp, vLp, vRp);
        body<0, RE, 2>(T + 6, S, ip, op, lane, wv, c0, sE, sO, gLp, gRp, vLp, vRp);
    }
    body<1, RE, 2>(y0 + 34, S, ip, op, lane, wv, c0, sE, sO, gLp, gRp, vLp, vRp);
    body<2, RE, 2>(y0 + 36, S, ip, op, lane, wv, c0, sE, sO, gLp, gRp, vLp, vRp);
    body<3, RE, 2>(y0 + 38, S, ip, op, lane, wv, c0, sE, sO, gLp, gRp, vLp, vRp);
    // last body: stores only row y0+31 (row y0+32 belongs to the next chunk)
    body<0, RE, 3>(y0 + 40, S, ip, op, lane, wv, c0, sE, sO, gLp, gRp, vLp, vRp);
}

__global__ __launch_bounds__(NT) void gradmap_pipe2_kernel(
        const float* __restrict__ img, float* __restrict__ out) {
    const int plane = blockIdx.y;
    const int y0 = blockIdx.x * CH;
    const int tid = threadIdx.x;
    const int lane = tid & 63;
    const int wv = tid >> 6;
    const int c0 = tid << 2;
    const float* ip = img + (size_t)plane * Hd * Wd + c0;
    float*       op = out + (size_t)plane * Hd * Wd + c0;

    // img rings: even rows (2 slots), odd rows (4 slots) — slot = pair-index mod ring
    __shared__ float s_imgE[2][SROW];
    __shared__ float s_imgO[4][SROW];
    __shared__ float s_gL[2][2][NW], s_gR[2][2][NW];  // [parity][row-in-pair][wave]
    __shared__ float s_vL[2][2][NW], s_vR[2][2][NW];

    if (blockIdx.x == 0 || blockIdx.x == gridDim.x - 1)
        sweep<true >(ip, op, y0, tid, lane, wv, c0, s_imgE, s_imgO, s_gL, s_gR, s_vL, s_vR);
    else
        sweep<false>(ip, op, y0, tid, lane, wv, c0, s_imgE, s_imgO, s_gL, s_gR, s_vL, s_vR);
}

extern "C" void kernel_launch(void* const* d_in, const int* in_sizes, int n_in,
                              void* d_out, int out_size, void* d_ws, size_t ws_size,
                              hipStream_t stream) {
    const float* img = (const float*)d_in[0];
    float* out = (float*)d_out;
    dim3 grid(Hd / CH, BC);   // 32 x 24 = 768 blocks = 3/CU, balanced
    dim3 block(NT);
    gradmap_pipe2_kernel<<<grid, block, 0, stream>>>(img, out);
}